// Round 21
// baseline (220.954 us; speedup 1.0000x reference)
//
#include <hip/hip_runtime.h>
#include <stdint.h>

// ---------------------------------------------------------------------------
// CausalMultiHeadSelfAttention  (B=4, S=2048, D=1024, H=16, Dh=64), fp32 I/O.
// bf16 MFMA pipeline. R21 = R20 (best, 188.2us) + fa widened to 64 q-rows
// per wave (MF=4, 256-row blocks, grid 64x8): halves the K/V LDS-read
// duplication per unit of work (fa is LDS-pipe-bound: ~41us of 90 is LDS
// instruction occupancy). LDS 70KB -> 2 blocks/CU; per-mf sa lifetime caps
// VGPR. gemm1 (LDS-transpose epilogue + fused k-rope), gemm2, cvt_all
// unchanged from R20.
// ---------------------------------------------------------------------------

typedef __attribute__((ext_vector_type(8))) short bf16x8;
typedef __attribute__((ext_vector_type(4))) float f32x4;
typedef __attribute__((ext_vector_type(8))) unsigned short u16x8;
typedef __attribute__((ext_vector_type(4))) unsigned short u16x4;
typedef __attribute__((ext_vector_type(4))) unsigned int u32x4;

#define NB 4
#define NS 2048
#define NH 16
#define DH 64
#define DM 1024
#define BH (NB*NH)

static __device__ __forceinline__ unsigned short f2bf(float f){
  unsigned u = __builtin_bit_cast(unsigned, f);
  u += 0x7fffu + ((u >> 16) & 1u);
  return (unsigned short)(u >> 16);
}
static __device__ __forceinline__ float bf2f(unsigned short h){
  unsigned u = ((unsigned)h) << 16;
  return __builtin_bit_cast(float, u);
}
static __device__ __forceinline__ unsigned cvt_pk_bf16(float lo, float hi){
  unsigned r;
  asm("v_cvt_pk_bf16_f32 %0, %1, %2" : "=v"(r) : "v"(lo), "v"(hi));
  return r;
}
static __device__ __forceinline__ f32x4 mfma16(bf16x8 a, bf16x8 b, f32x4 c){
  return __builtin_amdgcn_mfma_f32_16x16x32_bf16(a, b, c, 0, 0, 0);
}
static __device__ __forceinline__ void gld_lds16(const void* g, void* l){
  __builtin_amdgcn_global_load_lds((const __attribute__((address_space(1))) unsigned int*)g,
                                   (__attribute__((address_space(3))) unsigned int*)l,
                                   16, 0, 0);
}

// ---------------- fused fp32 -> bf16 converts + rope table -----------------
__global__ __launch_bounds__(256) void cvt_all(const float* __restrict__ x,
                                               const float* __restrict__ wqkv,
                                               const float* __restrict__ wo,
                                               const int* __restrict__ pos,
                                               unsigned short* __restrict__ xb,
                                               unsigned short* __restrict__ wqkvb,
                                               unsigned short* __restrict__ wob,
                                               float* __restrict__ ct,
                                               float* __restrict__ st){
  int stride = gridDim.x * blockDim.x;
  for (int i = blockIdx.x * blockDim.x + threadIdx.x; i < 3211264; i += stride){
    if (i < 3145728){
      const float* src; unsigned short* dst; int j;
      if (i < 2097152){ src = x; dst = xb; j = i; }
      else if (i < 2883584){ src = wqkv; dst = wqkvb; j = i - 2097152; }
      else { src = wo; dst = wob; j = i - 2883584; }
      f32x4 v = *(const f32x4*)(src + (size_t)j * 4);
      u16x4 o;
      o[0] = f2bf(v[0]); o[1] = f2bf(v[1]); o[2] = f2bf(v[2]); o[3] = f2bf(v[3]);
      *(u16x4*)(dst + (size_t)j * 4) = o;
    } else {
      int t = i - 3145728;
      int s = t >> 5, fi = t & 31;
      float p = (float)pos[s];
      float freq = exp2f(-(float)(2 * fi) * (13.287712379549449f / 64.f));
      float a = p * freq;
      ct[t] = cosf(a);
      st[t] = sinf(a);
    }
  }
}

// ------------------- pipelined GEMM, RING-deep LDS ring --------------------
// C = A[M][K] * B[N][K]^T, bf16 in, fp32 accum. BK=32. RING-deep LDS ring,
// counted vmcnt ladder, ONE barrier per K-step, XOR swizzle both sides.
// EPI=0 (gemm1): LDS-transpose epilogue -> coalesced 16B stores to
//   q,k [BH][S][64] (k roped inline from ct/st), vt [BH][64][S].
// EPI=1 (gemm2): fp32 C[M][N] direct.
template<int BM, int BN, int MF, int NFR, int EPI, int RING, int OCC>
__global__ __launch_bounds__((BM/(MF*16))*(BN/(NFR*16))*64, OCC)
void gemm_ring(const unsigned short* __restrict__ A,
               const unsigned short* __restrict__ Bm,
               void* __restrict__ out0, void* __restrict__ out1,
               void* __restrict__ out2,
               const float* __restrict__ ct_, const float* __restrict__ st_,
               int M, int N, int K){
  constexpr int WM = BM / (MF * 16);
  constexpr int WN = BN / (NFR * 16);
  constexpr int T  = WM * WN * 64;
  constexpr int LA = BM * 4 / T;
  constexpr int LB = BN * 4 / T;
  constexpr int L  = LA + LB;
  constexpr unsigned RB = (unsigned)RING * (BM + BN) * 64;      // ring bytes
  constexpr unsigned EB = (EPI == 0) ? (unsigned)(128 * 132 * 2) : 0u;
  constexpr unsigned SB = RB > EB ? RB : EB;
  __shared__ __attribute__((aligned(16))) unsigned char smem[SB];
  unsigned short* As = (unsigned short*)smem;                    // [RING][BM*32]
  unsigned short* Bs = As + (size_t)RING * BM * 32;              // [RING][BN*32]
  int tid = threadIdx.x;
  int w = tid >> 6, l = tid & 63;
  int lr = l & 15, lk = l >> 4;
  int m0 = blockIdx.y * BM, n0 = blockIdx.x * BN;
  int wr = (w / WN) * (MF * 16), wc = (w % WN) * (NFR * 16);

  const int nt = K >> 5;

  auto stage = [&](int t, int buf){
    int k0 = t * 32;
#pragma unroll
    for (int i = 0; i < LA; i++){
      int f = i * T + tid;
      int row = f >> 2, c = f & 3;
      int gc = (c ^ ((row >> 1) & 3)) * 8;
      gld_lds16(A + (size_t)(m0 + row) * K + k0 + gc, &As[(size_t)buf * BM * 32 + (i * T + w * 64) * 8]);
    }
#pragma unroll
    for (int i = 0; i < LB; i++){
      int f = i * T + tid;
      int row = f >> 2, c = f & 3;
      int gc = (c ^ ((row >> 1) & 3)) * 8;
      gld_lds16(Bm + (size_t)(n0 + row) * K + k0 + gc, &Bs[(size_t)buf * BN * 32 + (i * T + w * 64) * 8]);
    }
  };

  f32x4 zero = {0.f, 0.f, 0.f, 0.f};
  f32x4 acc[MF][NFR];
#pragma unroll
  for (int a = 0; a < MF; a++)
#pragma unroll
    for (int b = 0; b < NFR; b++) acc[a][b] = zero;

#pragma unroll
  for (int p = 0; p < RING - 1; p++) stage(p, p);
  asm volatile("s_waitcnt vmcnt(%0)" :: "i"((RING - 2) * L) : "memory");
  __builtin_amdgcn_sched_barrier(0);
  __builtin_amdgcn_s_barrier();
  __builtin_amdgcn_sched_barrier(0);

  int buf = 0;
  for (int t = 0; t < nt; ++t){
    bf16x8 af[MF], bfr[NFR];
#pragma unroll
    for (int mf = 0; mf < MF; mf++){
      int row = wr + mf * 16 + lr;
      af[mf] = *(const bf16x8*)&As[(size_t)buf * BM * 32 + row * 32 + ((lk ^ ((row >> 1) & 3)) * 8)];
    }
#pragma unroll
    for (int nf = 0; nf < NFR; nf++){
      int row = wc + nf * 16 + lr;
      bfr[nf] = *(const bf16x8*)&Bs[(size_t)buf * BN * 32 + row * 32 + ((lk ^ ((row >> 1) & 3)) * 8)];
    }
    if (t + RING - 1 < nt){
      int sb = buf - 1; if (sb < 0) sb = RING - 1;
      stage(t + RING - 1, sb);
    }
    __builtin_amdgcn_s_setprio(1);
#pragma unroll
    for (int mf = 0; mf < MF; mf++)
#pragma unroll
      for (int nf = 0; nf < NFR; nf++)
        acc[mf][nf] = mfma16(af[mf], bfr[nf], acc[mf][nf]);
    __builtin_amdgcn_s_setprio(0);
    if (RING >= 4){
      if (t + 3 < nt)      { asm volatile("s_waitcnt vmcnt(%0)" :: "i"(2 * L) : "memory"); }
      else if (t + 2 < nt) { asm volatile("s_waitcnt vmcnt(%0)" :: "i"(L) : "memory"); }
      else if (t + 1 < nt) { asm volatile("s_waitcnt vmcnt(0)" ::: "memory"); }
    } else {
      if (t + 2 < nt)      { asm volatile("s_waitcnt vmcnt(%0)" :: "i"(L) : "memory"); }
      else if (t + 1 < nt) { asm volatile("s_waitcnt vmcnt(0)" ::: "memory"); }
    }
    __builtin_amdgcn_sched_barrier(0);
    __builtin_amdgcn_s_barrier();
    __builtin_amdgcn_sched_barrier(0);
    buf = buf + 1; if (buf == RING) buf = 0;
  }

  if (EPI == 0){
    // ---------------- LDS-transpose epilogue (BM=BN=128) ----------------
    unsigned short* q  = (unsigned short*)out0;
    unsigned short* k  = (unsigned short*)out1;
    unsigned short* vt = (unsigned short*)out2;
    unsigned short* sm = (unsigned short*)smem;
    int part = n0 >> 10;                 // block-uniform (n0 % 128 == 0)
    int b = m0 >> 11;                    // block-uniform (BM=128 < 2048)
    __syncthreads();                     // ring reads done; reuse LDS
    if (part == 2){
      // phase A: acc -> LDS [n][m], stride 130
#pragma unroll
      for (int mf = 0; mf < MF; mf++)
#pragma unroll
        for (int nf = 0; nf < NFR; nf++)
#pragma unroll
          for (int j = 0; j < 4; j++)
            sm[(wc + nf * 16 + lr) * 130 + (wr + mf * 16 + lk * 4 + j)] = f2bf(acc[mf][nf][j]);
      __syncthreads();
      // phase B: coalesced rows of vt (s-contiguous)
      int nrow = tid >> 1, mh = tid & 1;
      int n = n0 + nrow;
      int h = (n & 1023) >> 6, dh = n & 63;
      int s0 = (m0 & (NS - 1)) + mh * 64;
      unsigned short* dst = vt + ((size_t)((b * NH + h) * DH + dh)) * NS + s0;
      const unsigned short* srcr = &sm[nrow * 130 + mh * 64];
#pragma unroll
      for (int ch = 0; ch < 8; ch++)
        *(u16x8*)(dst + ch * 8) = *(const u16x8*)(srcr + ch * 8);
    } else {
      // phase A: acc -> LDS [m][n], stride 132
#pragma unroll
      for (int mf = 0; mf < MF; mf++)
#pragma unroll
        for (int nf = 0; nf < NFR; nf++)
#pragma unroll
          for (int j = 0; j < 4; j++)
            sm[(wr + mf * 16 + lk * 4 + j) * 132 + (wc + nf * 16 + lr)] = f2bf(acc[mf][nf][j]);
      __syncthreads();
      // phase B: coalesced rows of q/k [bh][s][64]; rope k inline
      int mrow = tid >> 1, hh = tid & 1;
      int s = (m0 + mrow) & (NS - 1);
      int c0 = (n0 & 1023) + hh * 64;
      int h = c0 >> 6;
      unsigned short* dst = ((part == 0) ? q : k) + ((size_t)((b * NH + h) * NS + s)) * DH;
      const unsigned short* srcr = &sm[mrow * 132 + hh * 64];
      if (part == 1){
        const float* ctr = ct_ + s * 32;
        const float* str = st_ + s * 32;
#pragma unroll
        for (int ch = 0; ch < 8; ch++){
          u16x8 v = *(const u16x8*)(srcr + ch * 8);
          f32x4 cc = *(const f32x4*)(ctr + ch * 4);
          f32x4 ss = *(const f32x4*)(str + ch * 4);
          u16x8 o;
#pragma unroll
          for (int p = 0; p < 4; p++){
            float x1 = bf2f(v[2*p]), x2 = bf2f(v[2*p+1]);
            o[2*p]   = f2bf(x1 * cc[p] - x2 * ss[p]);
            o[2*p+1] = f2bf(x1 * ss[p] + x2 * cc[p]);
          }
          *(u16x8*)(dst + ch * 8) = o;
        }
      } else {
#pragma unroll
        for (int ch = 0; ch < 8; ch++)
          *(u16x8*)(dst + ch * 8) = *(const u16x8*)(srcr + ch * 8);
      }
    }
  } else {
    float* C = (float*)out0;
#pragma unroll
    for (int mf = 0; mf < MF; mf++)
#pragma unroll
      for (int nf = 0; nf < NFR; nf++)
#pragma unroll
        for (int j = 0; j < 4; j++){
          int m = m0 + wr + mf * 16 + lk * 4 + j;
          int n = n0 + wc + nf * 16 + lr;
          C[(size_t)m * N + n] = acc[mf][nf][j];
        }
  }
}

// ----------------------------- flash attention -----------------------------
// R21: 4-wave blocks, 64 q-rows PER WAVE (256 per block). grid (64 bh, 8 yb);
// qb = {7,6,5,4,0,1,2,3}[yb] pairs long+short blocks per CU. K/V^T LDS double
// buffers (XOR swizzle both sides) shared by all waves — halved read
// duplication per unit work vs 32-row waves. Swapped QK^T with fused q-rope
// (SC folded); bias-free P = exp2(s); packed P (stride 76); ones-MFMA row
// sums; per-mf sa lifetime. 2 blocks/CU.
__global__ __launch_bounds__(256, 2) void fa_kernel(const unsigned short* __restrict__ qb_,
                                                    const unsigned short* __restrict__ kbuf,
                                                    const unsigned short* __restrict__ vtb,
                                                    unsigned short* __restrict__ yb,
                                                    const float* __restrict__ ct_,
                                                    const float* __restrict__ st_){
  __shared__ __attribute__((aligned(16))) unsigned short Kl[2][4096];
  __shared__ __attribute__((aligned(16))) unsigned short Vl[2][4096];
  __shared__ __attribute__((aligned(16))) unsigned short Pl[4][64 * 76];
  int tid = threadIdx.x;
  int w = tid >> 6, l = tid & 63;
  int lr = l & 15, lk = l >> 4;
  int yb_ = blockIdx.y;
  int qb = (yb_ < 4) ? (7 - yb_) : (yb_ - 4);   // balanced longest-first
  int bh = blockIdx.x;
  int b = bh >> 4, h = bh & 15;
  int qr0 = qb * 256 + w * 64;
  const unsigned short* Q  = qb_  + (size_t)bh * NS * DH;
  const unsigned short* Kp = kbuf + (size_t)bh * NS * DH;
  const unsigned short* VT = vtb  + (size_t)bh * DH * NS;
  unsigned short* Pw = &Pl[w][0];

  int r8  = l >> 3;
  int swc = ((l & 7) ^ (r8 & 7)) * 8;

  auto stage = [&](int buf, int t){
    int kbase = t * 64;
    if (w < 2){
#pragma unroll
      for (int ii = 0; ii < 4; ii++){
        int i = w * 4 + ii;
        gld_lds16(Kp + (size_t)(kbase + i * 8 + r8) * DH + swc, &Kl[buf][i * 512]);
      }
    } else {
#pragma unroll
      for (int ii = 0; ii < 4; ii++){
        int i = (w - 2) * 4 + ii;
        gld_lds16(VT + (size_t)(i * 8 + r8) * NS + kbase + swc, &Vl[buf][i * 512]);
      }
    }
  };

  // Q fragments with FUSED ROPE and softmax scale folded in (tables * SC).
  const float SC = 0.18033688011112042f;   // (1/8) * log2(e)
  bf16x8 qf[4][2];
#pragma unroll
  for (int mf = 0; mf < 4; mf++){
    int srow = qr0 + mf * 16 + lr;
    const unsigned short* qrow = Q + (size_t)srow * DH;
    const float* ctr = ct_ + srow * 32;
    const float* str = st_ + srow * 32;
#pragma unroll
    for (int ks = 0; ks < 2; ks++){
      u16x8 raw = *(const u16x8*)(qrow + ks * 32 + lk * 8);
      f32x4 cc = *(const f32x4*)(ctr + ks * 16 + lk * 4);
      f32x4 ss = *(const f32x4*)(str + ks * 16 + lk * 4);
      u32x4 wds;
#pragma unroll
      for (int p = 0; p < 4; p++){
        float c2 = cc[p] * SC, s2 = ss[p] * SC;
        float x1 = bf2f(raw[2*p]), x2 = bf2f(raw[2*p+1]);
        wds[p] = cvt_pk_bf16(x1 * c2 - x2 * s2, x1 * s2 + x2 * c2);
      }
      qf[mf][ks] = __builtin_bit_cast(bf16x8, wds);
    }
  }

  bf16x8 ones;
#pragma unroll
  for (int p = 0; p < 8; p++) ones[p] = (short)0x3F80;

  f32x4 zero = {0.f, 0.f, 0.f, 0.f};
  f32x4 O[4][4];
  f32x4 Ls[4];
#pragma unroll
  for (int mf = 0; mf < 4; mf++){
#pragma unroll
    for (int nf = 0; nf < 4; nf++) O[mf][nf] = zero;
    Ls[mf] = zero;
  }

  const int ntile = 4 * qb + 4;

  stage(0, 0);
  __syncthreads();

  int cur = 0;
  for (int t = 0; t < ntile; ++t){
    int kbase = t * 64;
    if (t + 1 < ntile) stage(cur ^ 1, t + 1);

    if (kbase <= qr0 + 63){
      // ---- K fragments (shared across all mf) ----
      bf16x8 kf[4][2];
#pragma unroll
      for (int nf = 0; nf < 4; nf++){
        int row = nf * 16 + lr;
        int ro = row * 64, sw = (row & 7) << 3;
#pragma unroll
        for (int ks = 0; ks < 2; ks++)
          kf[nf][ks] = *(const bf16x8*)&Kl[cur][ro + ((ks * 32 + lk * 8) ^ sw)];
      }
      bool domask = (kbase + 63 > qr0);

      // ---- per-mf: swapped QK^T -> softmax -> packed P write ----
#pragma unroll
      for (int mf = 0; mf < 4; mf++){
        f32x4 sa[4];
#pragma unroll
        for (int nf = 0; nf < 4; nf++) sa[nf] = zero;
#pragma unroll
        for (int nf = 0; nf < 4; nf++){
          sa[nf] = mfma16(kf[nf][0], qf[mf][0], sa[nf]);
          sa[nf] = mfma16(kf[nf][1], qf[mf][1], sa[nf]);
        }
        int qg = qr0 + mf * 16 + lr;
#pragma unroll
        for (int nf = 0; nf < 4; nf++){
          float p4[4];
#pragma unroll
          for (int j = 0; j < 4; j++){
            float xx = sa[nf][j];
            if (domask){
              int kg = kbase + nf * 16 + lk * 4 + j;
              if (kg > qg) xx = -__builtin_inff();
            }
            p4[j] = exp2f(xx);
          }
          unsigned d0 = cvt_pk_bf16(p4[0], p4[1]);
          unsigned d1 = cvt_pk_bf16(p4[2], p4[3]);
          int base = (mf * 16 + lr) * 76 + nf * 16 + lk * 4;
          *(unsigned*)&Pw[base]     = d0;
          *(unsigned*)&Pw[base + 2] = d1;
        }
      }

      // ---- PV + ones-MFMA row sums ----
      bf16x8 pf[4][2];
#pragma unroll
      for (int mf = 0; mf < 4; mf++)
#pragma unroll
        for (int ks = 0; ks < 2; ks++)
          pf[mf][ks] = *(const bf16x8*)&Pw[(mf * 16 + lr) * 76 + ks * 32 + lk * 8];
#pragma unroll
      for (int ks = 0; ks < 2; ks++)
#pragma unroll
        for (int nfd = 0; nfd < 4; nfd++){
          int row = nfd * 16 + lr;
          int ro = row * 64, sw = (row & 7) << 3;
          bf16x8 vf = *(const bf16x8*)&Vl[cur][ro + ((ks * 32 + lk * 8) ^ sw)];
#pragma unroll
          for (int mf = 0; mf < 4; mf++)
            O[mf][nfd] = mfma16(pf[mf][ks], vf, O[mf][nfd]);
        }
#pragma unroll
      for (int ks = 0; ks < 2; ks++)
#pragma unroll
        for (int mf = 0; mf < 4; mf++)
          Ls[mf] = mfma16(pf[mf][ks], ones, Ls[mf]);
    }

    __syncthreads();
    cur ^= 1;
  }

  // epilogue: Ls in O's fragment layout -> lane-local division
#pragma unroll
  for (int mf = 0; mf < 4; mf++)
#pragma unroll
    for (int j = 0; j < 4; j++){
      float inv = 1.0f / Ls[mf][j];
      int srow = qr0 + mf * 16 + lk * 4 + j;
      unsigned short* yp = yb + ((size_t)(b * NS + srow)) * DM + h * DH;
#pragma unroll
      for (int nfd = 0; nfd < 4; nfd++)
        yp[nfd * 16 + lr] = f2bf(O[mf][nfd][j] * inv);
    }
}

// ---------------------------------------------------------------------------
extern "C" void kernel_launch(void* const* d_in, const int* in_sizes, int n_in,
                              void* d_out, int out_size, void* d_ws, size_t ws_size,
                              hipStream_t stream){
  const float* x    = (const float*)d_in[0];
  const float* wqkv = (const float*)d_in[1];
  const float* wo   = (const float*)d_in[2];
  const int*   pos  = (const int*)d_in[3];
  float* out = (float*)d_out;

  char* ws = (char*)d_ws;
  size_t off = 0;
  auto alloc = [&](size_t bytes) -> void* {
    void* p = ws + off;
    off += (bytes + 255) & ~(size_t)255;
    return p;
  };
  const size_t NE = (size_t)BH * NS * DH;            // 8,388,608 elems
  unsigned short* xb    = (unsigned short*)alloc((size_t)8192 * 1024 * 2);
  unsigned short* wqkvb = (unsigned short*)alloc((size_t)3072 * 1024 * 2);
  unsigned short* wob   = (unsigned short*)alloc((size_t)1024 * 1024 * 2);
  unsigned short* q  = (unsigned short*)alloc(NE * 2);
  unsigned short* k  = (unsigned short*)alloc(NE * 2);
  unsigned short* vt = (unsigned short*)alloc(NE * 2);
  unsigned short* y  = (unsigned short*)alloc(NE * 2);
  float* ct = (float*)alloc((size_t)NS * 32 * 4);
  float* st = (float*)alloc((size_t)NS * 32 * 4);

  // 1) converts + rope table (single fused launch)
  cvt_all<<<3072, 256, 0, stream>>>(x, wqkv, wo, pos, xb, wqkvb, wob, ct, st);
  // 2) qkv projection + head split; k roped in epilogue
  gemm_ring<128, 128, 4, 4, 0, 3, 3><<<dim3(24, 64), 256, 0, stream>>>(
      xb, wqkvb, q, k, vt, ct, st, 8192, 3072, 1024);
  // 3) causal flash attention (64 q-rows/wave, 2 blocks/CU)
  fa_kernel<<<dim3(64, 8), 256, 0, stream>>>(q, k, vt, y, ct, st);
  // 4) output projection -> fp32 out (128x128 ring-4)
  gemm_ring<128, 128, 4, 4, 1, 4, 2><<<dim3(8, 64), 256, 0, stream>>>(
      y, wob, out, nullptr, nullptr, nullptr, nullptr, 8192, 1024, 1024);
}

// Round 22
// 187.330 us; speedup vs baseline: 1.1795x; 1.1795x over previous
//
#include <hip/hip_runtime.h>
#include <stdint.h>

// ---------------------------------------------------------------------------
// CausalMultiHeadSelfAttention  (B=4, S=2048, D=1024, H=16, Dh=64), fp32 I/O.
// bf16 MFMA pipeline. R22 = R20 (best, 188.2us) + fa micro-polish:
//  - s_setprio(1) around QK^T and PV MFMA clusters (T5)
//  - P writes as single ds_write_b64 (uint2), halving P-write instrs
// gemm1 (ring-3 + LDS-transpose epilogue + fused k-rope), gemm2 ring-4,
// cvt_all(+rope table), fa structure (3 blocks/CU) unchanged from R20.
// ---------------------------------------------------------------------------

typedef __attribute__((ext_vector_type(8))) short bf16x8;
typedef __attribute__((ext_vector_type(4))) float f32x4;
typedef __attribute__((ext_vector_type(8))) unsigned short u16x8;
typedef __attribute__((ext_vector_type(4))) unsigned short u16x4;
typedef __attribute__((ext_vector_type(4))) unsigned int u32x4;

#define NB 4
#define NS 2048
#define NH 16
#define DH 64
#define DM 1024
#define BH (NB*NH)

static __device__ __forceinline__ unsigned short f2bf(float f){
  unsigned u = __builtin_bit_cast(unsigned, f);
  u += 0x7fffu + ((u >> 16) & 1u);
  return (unsigned short)(u >> 16);
}
static __device__ __forceinline__ float bf2f(unsigned short h){
  unsigned u = ((unsigned)h) << 16;
  return __builtin_bit_cast(float, u);
}
static __device__ __forceinline__ unsigned cvt_pk_bf16(float lo, float hi){
  unsigned r;
  asm("v_cvt_pk_bf16_f32 %0, %1, %2" : "=v"(r) : "v"(lo), "v"(hi));
  return r;
}
static __device__ __forceinline__ f32x4 mfma16(bf16x8 a, bf16x8 b, f32x4 c){
  return __builtin_amdgcn_mfma_f32_16x16x32_bf16(a, b, c, 0, 0, 0);
}
static __device__ __forceinline__ void gld_lds16(const void* g, void* l){
  __builtin_amdgcn_global_load_lds((const __attribute__((address_space(1))) unsigned int*)g,
                                   (__attribute__((address_space(3))) unsigned int*)l,
                                   16, 0, 0);
}

// ---------------- fused fp32 -> bf16 converts + rope table -----------------
__global__ __launch_bounds__(256) void cvt_all(const float* __restrict__ x,
                                               const float* __restrict__ wqkv,
                                               const float* __restrict__ wo,
                                               const int* __restrict__ pos,
                                               unsigned short* __restrict__ xb,
                                               unsigned short* __restrict__ wqkvb,
                                               unsigned short* __restrict__ wob,
                                               float* __restrict__ ct,
                                               float* __restrict__ st){
  int stride = gridDim.x * blockDim.x;
  for (int i = blockIdx.x * blockDim.x + threadIdx.x; i < 3211264; i += stride){
    if (i < 3145728){
      const float* src; unsigned short* dst; int j;
      if (i < 2097152){ src = x; dst = xb; j = i; }
      else if (i < 2883584){ src = wqkv; dst = wqkvb; j = i - 2097152; }
      else { src = wo; dst = wob; j = i - 2883584; }
      f32x4 v = *(const f32x4*)(src + (size_t)j * 4);
      u16x4 o;
      o[0] = f2bf(v[0]); o[1] = f2bf(v[1]); o[2] = f2bf(v[2]); o[3] = f2bf(v[3]);
      *(u16x4*)(dst + (size_t)j * 4) = o;
    } else {
      int t = i - 3145728;
      int s = t >> 5, fi = t & 31;
      float p = (float)pos[s];
      float freq = exp2f(-(float)(2 * fi) * (13.287712379549449f / 64.f));
      float a = p * freq;
      ct[t] = cosf(a);
      st[t] = sinf(a);
    }
  }
}

// ------------------- pipelined GEMM, RING-deep LDS ring --------------------
// C = A[M][K] * B[N][K]^T, bf16 in, fp32 accum. BK=32. RING-deep LDS ring,
// counted vmcnt ladder, ONE barrier per K-step, XOR swizzle both sides.
// EPI=0 (gemm1): LDS-transpose epilogue -> coalesced 16B stores to
//   q,k [BH][S][64] (k roped inline from ct/st), vt [BH][64][S].
// EPI=1 (gemm2): fp32 C[M][N] direct.
template<int BM, int BN, int MF, int NFR, int EPI, int RING, int OCC>
__global__ __launch_bounds__((BM/(MF*16))*(BN/(NFR*16))*64, OCC)
void gemm_ring(const unsigned short* __restrict__ A,
               const unsigned short* __restrict__ Bm,
               void* __restrict__ out0, void* __restrict__ out1,
               void* __restrict__ out2,
               const float* __restrict__ ct_, const float* __restrict__ st_,
               int M, int N, int K){
  constexpr int WM = BM / (MF * 16);
  constexpr int WN = BN / (NFR * 16);
  constexpr int T  = WM * WN * 64;
  constexpr int LA = BM * 4 / T;
  constexpr int LB = BN * 4 / T;
  constexpr int L  = LA + LB;
  constexpr unsigned RB = (unsigned)RING * (BM + BN) * 64;      // ring bytes
  constexpr unsigned EB = (EPI == 0) ? (unsigned)(128 * 132 * 2) : 0u;
  constexpr unsigned SB = RB > EB ? RB : EB;
  __shared__ __attribute__((aligned(16))) unsigned char smem[SB];
  unsigned short* As = (unsigned short*)smem;                    // [RING][BM*32]
  unsigned short* Bs = As + (size_t)RING * BM * 32;              // [RING][BN*32]
  int tid = threadIdx.x;
  int w = tid >> 6, l = tid & 63;
  int lr = l & 15, lk = l >> 4;
  int m0 = blockIdx.y * BM, n0 = blockIdx.x * BN;
  int wr = (w / WN) * (MF * 16), wc = (w % WN) * (NFR * 16);

  const int nt = K >> 5;

  auto stage = [&](int t, int buf){
    int k0 = t * 32;
#pragma unroll
    for (int i = 0; i < LA; i++){
      int f = i * T + tid;
      int row = f >> 2, c = f & 3;
      int gc = (c ^ ((row >> 1) & 3)) * 8;
      gld_lds16(A + (size_t)(m0 + row) * K + k0 + gc, &As[(size_t)buf * BM * 32 + (i * T + w * 64) * 8]);
    }
#pragma unroll
    for (int i = 0; i < LB; i++){
      int f = i * T + tid;
      int row = f >> 2, c = f & 3;
      int gc = (c ^ ((row >> 1) & 3)) * 8;
      gld_lds16(Bm + (size_t)(n0 + row) * K + k0 + gc, &Bs[(size_t)buf * BN * 32 + (i * T + w * 64) * 8]);
    }
  };

  f32x4 zero = {0.f, 0.f, 0.f, 0.f};
  f32x4 acc[MF][NFR];
#pragma unroll
  for (int a = 0; a < MF; a++)
#pragma unroll
    for (int b = 0; b < NFR; b++) acc[a][b] = zero;

#pragma unroll
  for (int p = 0; p < RING - 1; p++) stage(p, p);
  asm volatile("s_waitcnt vmcnt(%0)" :: "i"((RING - 2) * L) : "memory");
  __builtin_amdgcn_sched_barrier(0);
  __builtin_amdgcn_s_barrier();
  __builtin_amdgcn_sched_barrier(0);

  int buf = 0;
  for (int t = 0; t < nt; ++t){
    bf16x8 af[MF], bfr[NFR];
#pragma unroll
    for (int mf = 0; mf < MF; mf++){
      int row = wr + mf * 16 + lr;
      af[mf] = *(const bf16x8*)&As[(size_t)buf * BM * 32 + row * 32 + ((lk ^ ((row >> 1) & 3)) * 8)];
    }
#pragma unroll
    for (int nf = 0; nf < NFR; nf++){
      int row = wc + nf * 16 + lr;
      bfr[nf] = *(const bf16x8*)&Bs[(size_t)buf * BN * 32 + row * 32 + ((lk ^ ((row >> 1) & 3)) * 8)];
    }
    if (t + RING - 1 < nt){
      int sb = buf - 1; if (sb < 0) sb = RING - 1;
      stage(t + RING - 1, sb);
    }
    __builtin_amdgcn_s_setprio(1);
#pragma unroll
    for (int mf = 0; mf < MF; mf++)
#pragma unroll
      for (int nf = 0; nf < NFR; nf++)
        acc[mf][nf] = mfma16(af[mf], bfr[nf], acc[mf][nf]);
    __builtin_amdgcn_s_setprio(0);
    if (RING >= 4){
      if (t + 3 < nt)      { asm volatile("s_waitcnt vmcnt(%0)" :: "i"(2 * L) : "memory"); }
      else if (t + 2 < nt) { asm volatile("s_waitcnt vmcnt(%0)" :: "i"(L) : "memory"); }
      else if (t + 1 < nt) { asm volatile("s_waitcnt vmcnt(0)" ::: "memory"); }
    } else {
      if (t + 2 < nt)      { asm volatile("s_waitcnt vmcnt(%0)" :: "i"(L) : "memory"); }
      else if (t + 1 < nt) { asm volatile("s_waitcnt vmcnt(0)" ::: "memory"); }
    }
    __builtin_amdgcn_sched_barrier(0);
    __builtin_amdgcn_s_barrier();
    __builtin_amdgcn_sched_barrier(0);
    buf = buf + 1; if (buf == RING) buf = 0;
  }

  if (EPI == 0){
    // ---------------- LDS-transpose epilogue (BM=BN=128) ----------------
    unsigned short* q  = (unsigned short*)out0;
    unsigned short* k  = (unsigned short*)out1;
    unsigned short* vt = (unsigned short*)out2;
    unsigned short* sm = (unsigned short*)smem;
    int part = n0 >> 10;                 // block-uniform (n0 % 128 == 0)
    int b = m0 >> 11;                    // block-uniform (BM=128 < 2048)
    __syncthreads();                     // ring reads done; reuse LDS
    if (part == 2){
      // phase A: acc -> LDS [n][m], stride 130
#pragma unroll
      for (int mf = 0; mf < MF; mf++)
#pragma unroll
        for (int nf = 0; nf < NFR; nf++)
#pragma unroll
          for (int j = 0; j < 4; j++)
            sm[(wc + nf * 16 + lr) * 130 + (wr + mf * 16 + lk * 4 + j)] = f2bf(acc[mf][nf][j]);
      __syncthreads();
      // phase B: coalesced rows of vt (s-contiguous)
      int nrow = tid >> 1, mh = tid & 1;
      int n = n0 + nrow;
      int h = (n & 1023) >> 6, dh = n & 63;
      int s0 = (m0 & (NS - 1)) + mh * 64;
      unsigned short* dst = vt + ((size_t)((b * NH + h) * DH + dh)) * NS + s0;
      const unsigned short* srcr = &sm[nrow * 130 + mh * 64];
#pragma unroll
      for (int ch = 0; ch < 8; ch++)
        *(u16x8*)(dst + ch * 8) = *(const u16x8*)(srcr + ch * 8);
    } else {
      // phase A: acc -> LDS [m][n], stride 132
#pragma unroll
      for (int mf = 0; mf < MF; mf++)
#pragma unroll
        for (int nf = 0; nf < NFR; nf++)
#pragma unroll
          for (int j = 0; j < 4; j++)
            sm[(wr + mf * 16 + lk * 4 + j) * 132 + (wc + nf * 16 + lr)] = f2bf(acc[mf][nf][j]);
      __syncthreads();
      // phase B: coalesced rows of q/k [bh][s][64]; rope k inline
      int mrow = tid >> 1, hh = tid & 1;
      int s = (m0 + mrow) & (NS - 1);
      int c0 = (n0 & 1023) + hh * 64;
      int h = c0 >> 6;
      unsigned short* dst = ((part == 0) ? q : k) + ((size_t)((b * NH + h) * NS + s)) * DH;
      const unsigned short* srcr = &sm[mrow * 132 + hh * 64];
      if (part == 1){
        const float* ctr = ct_ + s * 32;
        const float* str = st_ + s * 32;
#pragma unroll
        for (int ch = 0; ch < 8; ch++){
          u16x8 v = *(const u16x8*)(srcr + ch * 8);
          f32x4 cc = *(const f32x4*)(ctr + ch * 4);
          f32x4 ss = *(const f32x4*)(str + ch * 4);
          u16x8 o;
#pragma unroll
          for (int p = 0; p < 4; p++){
            float x1 = bf2f(v[2*p]), x2 = bf2f(v[2*p+1]);
            o[2*p]   = f2bf(x1 * cc[p] - x2 * ss[p]);
            o[2*p+1] = f2bf(x1 * ss[p] + x2 * cc[p]);
          }
          *(u16x8*)(dst + ch * 8) = o;
        }
      } else {
#pragma unroll
        for (int ch = 0; ch < 8; ch++)
          *(u16x8*)(dst + ch * 8) = *(const u16x8*)(srcr + ch * 8);
      }
    }
  } else {
    float* C = (float*)out0;
#pragma unroll
    for (int mf = 0; mf < MF; mf++)
#pragma unroll
      for (int nf = 0; nf < NFR; nf++)
#pragma unroll
        for (int j = 0; j < 4; j++){
          int m = m0 + wr + mf * 16 + lk * 4 + j;
          int n = n0 + wc + nf * 16 + lr;
          C[(size_t)m * N + n] = acc[mf][nf][j];
        }
  }
}

// ----------------------------- flash attention -----------------------------
// R20 structure + setprio around MFMA clusters + b64 P writes.
// 4-wave blocks, 128 q-rows; grid (64 bh, 16 qb), longest-first. K/V^T LDS
// double buffers (XOR swizzle both sides); fused q-rope with SC folded;
// bias-free P = exp2(s); packed P (stride 76); ones-MFMA row sums.
__global__ __launch_bounds__(256, 3) void fa_kernel(const unsigned short* __restrict__ qb_,
                                                    const unsigned short* __restrict__ kbuf,
                                                    const unsigned short* __restrict__ vtb,
                                                    unsigned short* __restrict__ yb,
                                                    const float* __restrict__ ct_,
                                                    const float* __restrict__ st_){
  __shared__ __attribute__((aligned(16))) unsigned short Kl[2][4096];
  __shared__ __attribute__((aligned(16))) unsigned short Vl[2][4096];
  __shared__ __attribute__((aligned(16))) unsigned short Pl[4][32 * 76];
  int tid = threadIdx.x;
  int w = tid >> 6, l = tid & 63;
  int lr = l & 15, lk = l >> 4;
  int qb = 15 - blockIdx.y;
  int bh = blockIdx.x;
  int b = bh >> 4, h = bh & 15;
  int qr0 = qb * 128 + w * 32;
  const unsigned short* Q  = qb_  + (size_t)bh * NS * DH;
  const unsigned short* Kp = kbuf + (size_t)bh * NS * DH;
  const unsigned short* VT = vtb  + (size_t)bh * DH * NS;
  unsigned short* Pw = &Pl[w][0];

  int r8  = l >> 3;
  int swc = ((l & 7) ^ (r8 & 7)) * 8;

  auto stage = [&](int buf, int t){
    int kbase = t * 64;
    if (w < 2){
#pragma unroll
      for (int ii = 0; ii < 4; ii++){
        int i = w * 4 + ii;
        gld_lds16(Kp + (size_t)(kbase + i * 8 + r8) * DH + swc, &Kl[buf][i * 512]);
      }
    } else {
#pragma unroll
      for (int ii = 0; ii < 4; ii++){
        int i = (w - 2) * 4 + ii;
        gld_lds16(VT + (size_t)(i * 8 + r8) * NS + kbase + swc, &Vl[buf][i * 512]);
      }
    }
  };

  const float SC = 0.18033688011112042f;   // (1/8) * log2(e)
  bf16x8 qf[2][2];
#pragma unroll
  for (int mf = 0; mf < 2; mf++){
    int srow = qr0 + mf * 16 + lr;
    const unsigned short* qrow = Q + (size_t)srow * DH;
    const float* ctr = ct_ + srow * 32;
    const float* str = st_ + srow * 32;
#pragma unroll
    for (int ks = 0; ks < 2; ks++){
      u16x8 raw = *(const u16x8*)(qrow + ks * 32 + lk * 8);
      f32x4 cc = *(const f32x4*)(ctr + ks * 16 + lk * 4);
      f32x4 ss = *(const f32x4*)(str + ks * 16 + lk * 4);
      u32x4 wds;
#pragma unroll
      for (int p = 0; p < 4; p++){
        float c2 = cc[p] * SC, s2 = ss[p] * SC;
        float x1 = bf2f(raw[2*p]), x2 = bf2f(raw[2*p+1]);
        wds[p] = cvt_pk_bf16(x1 * c2 - x2 * s2, x1 * s2 + x2 * c2);
      }
      qf[mf][ks] = __builtin_bit_cast(bf16x8, wds);
    }
  }

  bf16x8 ones;
#pragma unroll
  for (int p = 0; p < 8; p++) ones[p] = (short)0x3F80;

  f32x4 zero = {0.f, 0.f, 0.f, 0.f};
  f32x4 O[2][4];
  f32x4 Ls[2];
#pragma unroll
  for (int mf = 0; mf < 2; mf++){
#pragma unroll
    for (int nf = 0; nf < 4; nf++) O[mf][nf] = zero;
    Ls[mf] = zero;
  }

  const int ntile = 2 * qb + 2;

  stage(0, 0);
  __syncthreads();

  int cur = 0;
  for (int t = 0; t < ntile; ++t){
    int kbase = t * 64;
    if (t + 1 < ntile) stage(cur ^ 1, t + 1);

    if (kbase <= qr0 + 31){
      bf16x8 kf[4][2];
#pragma unroll
      for (int nf = 0; nf < 4; nf++){
        int row = nf * 16 + lr;
        int ro = row * 64, sw = (row & 7) << 3;
#pragma unroll
        for (int ks = 0; ks < 2; ks++)
          kf[nf][ks] = *(const bf16x8*)&Kl[cur][ro + ((ks * 32 + lk * 8) ^ sw)];
      }
      bf16x8 vf[2][4];
#pragma unroll
      for (int nfd = 0; nfd < 4; nfd++){
        int row = nfd * 16 + lr;
        int ro = row * 64, sw = (row & 7) << 3;
#pragma unroll
        for (int ks = 0; ks < 2; ks++)
          vf[ks][nfd] = *(const bf16x8*)&Vl[cur][ro + ((ks * 32 + lk * 8) ^ sw)];
      }

      f32x4 sa[2][4];
#pragma unroll
      for (int mf = 0; mf < 2; mf++)
#pragma unroll
        for (int nf = 0; nf < 4; nf++) sa[mf][nf] = zero;
      __builtin_amdgcn_s_setprio(1);
#pragma unroll
      for (int nf = 0; nf < 4; nf++)
#pragma unroll
        for (int mf = 0; mf < 2; mf++){
          sa[mf][nf] = mfma16(kf[nf][0], qf[mf][0], sa[mf][nf]);
          sa[mf][nf] = mfma16(kf[nf][1], qf[mf][1], sa[mf][nf]);
        }
      __builtin_amdgcn_s_setprio(0);

      bool domask = (kbase + 63 > qr0);

#pragma unroll
      for (int mf = 0; mf < 2; mf++){
        int qg = qr0 + mf * 16 + lr;
#pragma unroll
        for (int nf = 0; nf < 4; nf++){
          float p4[4];
#pragma unroll
          for (int j = 0; j < 4; j++){
            float xx = sa[mf][nf][j];
            if (domask){
              int kg = kbase + nf * 16 + lk * 4 + j;
              if (kg > qg) xx = -__builtin_inff();
            }
            p4[j] = exp2f(xx);
          }
          uint2 dd;
          dd.x = cvt_pk_bf16(p4[0], p4[1]);
          dd.y = cvt_pk_bf16(p4[2], p4[3]);
          *(uint2*)&Pw[(mf * 16 + lr) * 76 + nf * 16 + lk * 4] = dd;
        }
      }

      bf16x8 pf[2][2];
#pragma unroll
      for (int mf = 0; mf < 2; mf++)
#pragma unroll
        for (int ks = 0; ks < 2; ks++)
          pf[mf][ks] = *(const bf16x8*)&Pw[(mf * 16 + lr) * 76 + ks * 32 + lk * 8];
      __builtin_amdgcn_s_setprio(1);
#pragma unroll
      for (int ks = 0; ks < 2; ks++)
#pragma unroll
        for (int nfd = 0; nfd < 4; nfd++)
#pragma unroll
          for (int mf = 0; mf < 2; mf++)
            O[mf][nfd] = mfma16(pf[mf][ks], vf[ks][nfd], O[mf][nfd]);
#pragma unroll
      for (int ks = 0; ks < 2; ks++)
#pragma unroll
        for (int mf = 0; mf < 2; mf++)
          Ls[mf] = mfma16(pf[mf][ks], ones, Ls[mf]);
      __builtin_amdgcn_s_setprio(0);
    }

    __syncthreads();
    cur ^= 1;
  }

#pragma unroll
  for (int mf = 0; mf < 2; mf++)
#pragma unroll
    for (int j = 0; j < 4; j++){
      float inv = 1.0f / Ls[mf][j];
      int srow = qr0 + mf * 16 + lk * 4 + j;
      unsigned short* yp = yb + ((size_t)(b * NS + srow)) * DM + h * DH;
#pragma unroll
      for (int nfd = 0; nfd < 4; nfd++)
        yp[nfd * 16 + lr] = f2bf(O[mf][nfd][j] * inv);
    }
}

// ---------------------------------------------------------------------------
extern "C" void kernel_launch(void* const* d_in, const int* in_sizes, int n_in,
                              void* d_out, int out_size, void* d_ws, size_t ws_size,
                              hipStream_t stream){
  const float* x    = (const float*)d_in[0];
  const float* wqkv = (const float*)d_in[1];
  const float* wo   = (const float*)d_in[2];
  const int*   pos  = (const int*)d_in[3];
  float* out = (float*)d_out;

  char* ws = (char*)d_ws;
  size_t off = 0;
  auto alloc = [&](size_t bytes) -> void* {
    void* p = ws + off;
    off += (bytes + 255) & ~(size_t)255;
    return p;
  };
  const size_t NE = (size_t)BH * NS * DH;            // 8,388,608 elems
  unsigned short* xb    = (unsigned short*)alloc((size_t)8192 * 1024 * 2);
  unsigned short* wqkvb = (unsigned short*)alloc((size_t)3072 * 1024 * 2);
  unsigned short* wob   = (unsigned short*)alloc((size_t)1024 * 1024 * 2);
  unsigned short* q  = (unsigned short*)alloc(NE * 2);
  unsigned short* k  = (unsigned short*)alloc(NE * 2);
  unsigned short* vt = (unsigned short*)alloc(NE * 2);
  unsigned short* y  = (unsigned short*)alloc(NE * 2);
  float* ct = (float*)alloc((size_t)NS * 32 * 4);
  float* st = (float*)alloc((size_t)NS * 32 * 4);

  // 1) converts + rope table (single fused launch)
  cvt_all<<<3072, 256, 0, stream>>>(x, wqkv, wo, pos, xb, wqkvb, wob, ct, st);
  // 2) qkv projection + head split; k roped in epilogue
  gemm_ring<128, 128, 4, 4, 0, 3, 3><<<dim3(24, 64), 256, 0, stream>>>(
      xb, wqkvb, q, k, vt, ct, st, 8192, 3072, 1024);
  // 3) causal flash attention (q-rope fused, ones-MFMA row sums, setprio)
  fa_kernel<<<dim3(64, 16), 256, 0, stream>>>(q, k, vt, y, ct, st);
  // 4) output projection -> fp32 out (128x128 ring-4)
  gemm_ring<128, 128, 4, 4, 1, 4, 2><<<dim3(8, 64), 256, 0, stream>>>(
      y, wob, out, nullptr, nullptr, nullptr, nullptr, 8192, 1024, 1024);
}